// Round 1
// baseline (586.270 us; speedup 1.0000x reference)
//
#include <hip/hip_runtime.h>

// Shapes fixed by the reference setup.
#define BB 32
#define HH 16
#define NN 1024
#define DD 128

// Kernel 1: score[g] = dot(t[g*D .. +D), w2) for g in [0, B*H*N).
// Half-wave (32 lanes) per row: lane l loads float4 at d=4l, shuffle-reduce.
__global__ __launch_bounds__(256) void score_kernel(const float* __restrict__ t,
                                                    const float* __restrict__ w2,
                                                    float* __restrict__ score) {
    const int tid  = threadIdx.x;
    const int wave = tid >> 6;        // 0..3
    const int lane = tid & 63;
    const int half = lane >> 5;       // 0 or 1
    const int l    = lane & 31;

    const float4 wv = ((const float4*)w2)[l];   // w2 is 512B-aligned offset (128 floats)

    // Block covers 64 consecutive global rows; each wave covers 16 (2 per iter).
    const long gbase = (long)blockIdx.x * 64 + (long)wave * 16 + half;
#pragma unroll
    for (int it = 0; it < 8; ++it) {
        const long g = gbase + (long)it * 2;
        const float4 tv = ((const float4*)(t + g * DD))[l];
        float p = tv.x * wv.x + tv.y * wv.y + tv.z * wv.z + tv.w * wv.w;
        p += __shfl_xor(p, 1);
        p += __shfl_xor(p, 2);
        p += __shfl_xor(p, 4);
        p += __shfl_xor(p, 8);
        p += __shfl_xor(p, 16);
        if (l == 0) score[g] = p;
    }
}

// Kernel 2: one block per (b,h) row. Computes padd[b] (first index where
// padding==0, else N), masked softmax over the row, and overwrites the score
// row in-place with factor[n] = 1 + attn[n].  Masked n -> factor = 1 exactly.
__global__ __launch_bounds__(256) void softmax_kernel(const int* __restrict__ padding,
                                                      float* __restrict__ score) {
    const int bh  = blockIdx.x;       // 0..B*H-1
    const int b   = bh >> 4;          // H = 16
    const int tid = threadIdx.x;

    __shared__ int   red_i[4];
    __shared__ float red_m[4];
    __shared__ float red_s[4];

    // ---- padd: min index with padding==0, else N ----
    const int* pb = padding + b * NN;
    int lm = NN;
#pragma unroll
    for (int k = 0; k < 4; ++k) {
        const int i = tid + k * 256;
        if (pb[i] == 0) lm = min(lm, i);
    }
#pragma unroll
    for (int off = 32; off; off >>= 1) lm = min(lm, __shfl_xor(lm, off));
    if ((tid & 63) == 0) red_i[tid >> 6] = lm;
    __syncthreads();
    const int padd = min(min(red_i[0], red_i[1]), min(red_i[2], red_i[3]));

    // ---- load this thread's 4 scores ----
    float* row = score + (long)bh * NN;
    const float4 sc = ((const float4*)row)[tid];
    const int n0 = tid * 4;

    // ---- masked max ----
    const float NEG = -3.4e38f;
    float m = (n0 + 0 < padd) ? sc.x : NEG;
    m = fmaxf(m, (n0 + 1 < padd) ? sc.y : NEG);
    m = fmaxf(m, (n0 + 2 < padd) ? sc.z : NEG);
    m = fmaxf(m, (n0 + 3 < padd) ? sc.w : NEG);
#pragma unroll
    for (int off = 32; off; off >>= 1) m = fmaxf(m, __shfl_xor(m, off));
    if ((tid & 63) == 0) red_m[tid >> 6] = m;
    __syncthreads();
    const float M = fmaxf(fmaxf(red_m[0], red_m[1]), fmaxf(red_m[2], red_m[3]));

    // ---- exp + sum ----
    const float e0 = (n0 + 0 < padd) ? __expf(sc.x - M) : 0.f;
    const float e1 = (n0 + 1 < padd) ? __expf(sc.y - M) : 0.f;
    const float e2 = (n0 + 2 < padd) ? __expf(sc.z - M) : 0.f;
    const float e3 = (n0 + 3 < padd) ? __expf(sc.w - M) : 0.f;
    float s = e0 + e1 + e2 + e3;
#pragma unroll
    for (int off = 32; off; off >>= 1) s += __shfl_xor(s, off);
    if ((tid & 63) == 0) red_s[tid >> 6] = s;
    __syncthreads();
    const float S = red_s[0] + red_s[1] + red_s[2] + red_s[3];

    const float inv = (S > 0.f) ? (1.0f / S) : 0.f;   // guard padd==0 (never in this dist)
    float4 f4;
    f4.x = 1.f + e0 * inv;
    f4.y = 1.f + e1 * inv;
    f4.z = 1.f + e2 * inv;
    f4.w = 1.f + e3 * inv;
    ((float4*)row)[tid] = f4;
}

// Kernel 3: out = t * factor[row].  Pure streaming, float4.
__global__ __launch_bounds__(256) void mul_kernel(const float* __restrict__ t,
                                                  const float* __restrict__ factor,
                                                  float* __restrict__ out) {
    const long g4 = (long)blockIdx.x * 256 + threadIdx.x;   // float4 index
    const float f = factor[g4 >> 5];                        // 32 float4 per D=128 row
    float4 v = ((const float4*)t)[g4];
    v.x *= f; v.y *= f; v.z *= f; v.w *= f;
    ((float4*)out)[g4] = v;
}

extern "C" void kernel_launch(void* const* d_in, const int* in_sizes, int n_in,
                              void* d_out, int out_size, void* d_ws, size_t ws_size,
                              hipStream_t stream) {
    // inputs: 0 t_1 (unused — softmax shift-invariance), 1 t, 2 padding, 3 N,
    //         4 concat_w (w1 unused | w2), 5 concat_b (unused — cancels)
    const float* t       = (const float*)d_in[1];
    const int*   padding = (const int*)d_in[2];
    const float* cw      = (const float*)d_in[4];
    float*       out     = (float*)d_out;
    float*       score   = (float*)d_ws;   // B*H*N floats = 2 MB, reused as factor

    const int total_rows = BB * HH * NN;            // 524288
    score_kernel<<<total_rows / 64, 256, 0, stream>>>(t, cw + DD, score);
    softmax_kernel<<<BB * HH, 256, 0, stream>>>(padding, score);
    const long total4 = (long)BB * HH * NN * DD / 4;  // 16777216
    mul_kernel<<<(int)(total4 / 256), 256, 0, stream>>>(t, score, out);
}